// Round 4
// baseline (369.192 us; speedup 1.0000x reference)
//
#include <hip/hip_runtime.h>

typedef __attribute__((ext_vector_type(8))) short bf16x8;
typedef __attribute__((ext_vector_type(4))) float f32x4;

constexpr int BT   = 256;   // threads/block (4 waves)
constexpr int TP   = 64;    // pairs per tile (16 per wave)
constexpr int KD   = 96;    // feature/hidden dim
constexpr int LDX  = 104;   // row stride in bf16 (208 B, 16B-aligned)
constexpr int NBLK = 512;   // persistent blocks (2 per CU)

__device__ inline ushort f2bf(float f) {  // fp32 -> bf16 RNE
    uint u = __float_as_uint(f);
    u += 0x7fffu + ((u >> 16) & 1u);
    return (ushort)(u >> 16);
}

// prep: geoms f32 -> bf16 table in d_ws
__global__ void prep_geoms(const float* __restrict__ g, ushort* __restrict__ gb, int n) {
    int i = blockIdx.x * 256 + threadIdx.x;
    if (i < n) gb[i] = f2bf(g[i]);
}

__global__ void __launch_bounds__(BT, 2) collision_mfma(
    const int* __restrict__ o1, const int* __restrict__ o2,
    const float* __restrict__ Tg, const float* __restrict__ geoms,
    const ushort* __restrict__ gbf,
    const float* __restrict__ W1, const float* __restrict__ b1,
    const float* __restrict__ W2, const float* __restrict__ b2,
    const float* __restrict__ W3, const float* __restrict__ b3,
    float* __restrict__ out, int N)
{
    __shared__ ushort xs[128 * LDX];    // x/h tile bf16, wave-private 32-row bands
    __shared__ ushort w1t[KD * LDX];    // W1^T bf16 [n][k]
    __shared__ ushort w2t[KD * LDX];    // W2^T bf16 [n][k]
    __shared__ float  tinv[64 * 16];    // per-pair inverse rows 0..2, stride 16

    const int tid = threadIdx.x;
    const int w   = tid >> 6;      // wave 0..3
    const int l   = tid & 63;      // lane
    const int cl  = l & 15;        // fragment col within 16-tile
    const int g   = l >> 4;        // k-group 0..3
    const int rg  = g * 4;

    // ---- stage weights once: wt[n][k] = W[k][n], bf16 ----
    for (int i = tid; i < KD * KD; i += BT) {
        int k = i / KD;
        int n = i - k * KD;
        w1t[n * LDX + k] = f2bf(W1[i]);
        w2t[n * LDX + k] = f2bf(W2[i]);
    }
    __syncthreads();   // only barrier; main loop is wave-private

    const int ntiles = N / TP;

    for (int tile = blockIdx.x; tile < ntiles; tile += NBLK) {
        const int pbase = tile * TP + w * 16;

        // ===== f64 4x4 inverse: lanes 0..15, one pair each (wave-private) =====
        if (l < 16) {
            const int p = pbase + l;
            const float4* T4 = reinterpret_cast<const float4*>(Tg + (size_t)p * 16);
            float4 t0 = T4[0], t1 = T4[1], t2 = T4[2], t3 = T4[3];
            double m00=t0.x, m01=t0.y, m02=t0.z, m03=t0.w;
            double m10=t1.x, m11=t1.y, m12=t1.z, m13=t1.w;
            double m20=t2.x, m21=t2.y, m22=t2.z, m23=t2.w;
            double m30=t3.x, m31=t3.y, m32=t3.z, m33=t3.w;
            double A2323 = m22*m33 - m23*m32;
            double A1323 = m21*m33 - m23*m31;
            double A1223 = m21*m32 - m22*m31;
            double A0323 = m20*m33 - m23*m30;
            double A0223 = m20*m32 - m22*m30;
            double A0123 = m20*m31 - m21*m30;
            double A2313 = m12*m33 - m13*m32;
            double A1313 = m11*m33 - m13*m31;
            double A1213 = m11*m32 - m12*m31;
            double A2312 = m12*m23 - m13*m22;
            double A1312 = m11*m23 - m13*m21;
            double A1212 = m11*m22 - m12*m21;
            double A0313 = m10*m33 - m13*m30;
            double A0213 = m10*m32 - m12*m30;
            double A0312 = m10*m23 - m13*m20;
            double A0212 = m10*m22 - m12*m20;
            double A0113 = m10*m31 - m11*m30;
            double A0112 = m10*m21 - m11*m20;
            double det = m00*(m11*A2323 - m12*A1323 + m13*A1223)
                       - m01*(m10*A2323 - m12*A0323 + m13*A0223)
                       + m02*(m10*A1323 - m11*A0323 + m13*A0123)
                       - m03*(m10*A1223 - m11*A0223 + m12*A0123);
            double idet = 1.0 / det;
            float* ti = &tinv[(w * 16 + l) * 16];
            ti[0]  = (float)( idet *  (m11*A2323 - m12*A1323 + m13*A1223) );
            ti[1]  = (float)( idet * -(m01*A2323 - m02*A1323 + m03*A1223) );
            ti[2]  = (float)( idet *  (m01*A2313 - m02*A1313 + m03*A1213) );
            ti[3]  = (float)( idet * -(m01*A2312 - m02*A1312 + m03*A1212) );
            ti[4]  = (float)( idet * -(m10*A2323 - m12*A0323 + m13*A0223) );
            ti[5]  = (float)( idet *  (m00*A2323 - m02*A0323 + m03*A0223) );
            ti[6]  = (float)( idet * -(m00*A2313 - m02*A0313 + m03*A0213) );
            ti[7]  = (float)( idet *  (m00*A2312 - m02*A0312 + m03*A0212) );
            ti[8]  = (float)( idet *  (m10*A1323 - m11*A0323 + m13*A0123) );
            ti[9]  = (float)( idet * -(m00*A1323 - m01*A0323 + m03*A0123) );
            ti[10] = (float)( idet *  (m00*A1313 - m01*A0313 + m03*A0113) );
            ti[11] = (float)( idet * -(m00*A1312 - m01*A0312 + m03*A0112) );
        }

        // ===== staging: lane = half-row. row = br*16+dp, part pt =====
        {
            const int rl = l & 31;          // local row 0..31
            const int pt = l >> 5;          // part: elems [pt*24, pt*24+24)
            const int br = rl >> 4;         // branch 0: (x1, T x2)  1: (x2, Tinv x1)
            const int dp = rl & 15;         // local pair
            const int p  = pbase + dp;
            const int ia = o1[p], ib = o2[p];
            const int oa = br ? ib : ia;
            const int ob = br ? ia : ib;
            ushort* xrow = xs + (w * 32 + rl) * LDX;

            // copy half (24 bf16 from pre-converted table)
            {
                const uint4* src = reinterpret_cast<const uint4*>(gbf + oa * 48 + pt * 24);
                uint4* dst = reinterpret_cast<uint4*>(xrow + pt * 24);
                dst[0] = src[0]; dst[1] = src[1]; dst[2] = src[2];
            }

            // transform half: 8 vec3s
            float4 M0, M1, M2;
            if (br == 0) {
                const float4* Tp = reinterpret_cast<const float4*>(Tg + (size_t)p * 16);
                M0 = Tp[0]; M1 = Tp[1]; M2 = Tp[2];
            } else {
                const float4* ti = reinterpret_cast<const float4*>(&tinv[(w * 16 + dp) * 16]);
                M0 = ti[0]; M1 = ti[1]; M2 = ti[2];
            }
            float v[24];
            {
                const float4* bs = reinterpret_cast<const float4*>(geoms + (size_t)ob * 48 + pt * 24);
                #pragma unroll
                for (int q = 0; q < 6; ++q) {
                    float4 t = bs[q];
                    v[4*q+0] = t.x; v[4*q+1] = t.y; v[4*q+2] = t.z; v[4*q+3] = t.w;
                }
            }
            union { ushort us[24]; uint4 q4[3]; } pk;
            #pragma unroll
            for (int m = 0; m < 8; ++m) {
                float vx = v[3*m+0], vy = v[3*m+1], vz = v[3*m+2];
                pk.us[3*m+0] = f2bf(fmaf(M0.x, vx, fmaf(M0.y, vy, fmaf(M0.z, vz, M0.w))));
                pk.us[3*m+1] = f2bf(fmaf(M1.x, vx, fmaf(M1.y, vy, fmaf(M1.z, vz, M1.w))));
                pk.us[3*m+2] = f2bf(fmaf(M2.x, vx, fmaf(M2.y, vy, fmaf(M2.z, vz, M2.w))));
            }
            uint4* dst = reinterpret_cast<uint4*>(xrow + 48 + pt * 24);
            dst[0] = pk.q4[0]; dst[1] = pk.q4[1]; dst[2] = pk.q4[2];
        }

        // ===== layer 1: acc[mt][nt] = b1 + W1^T-frag x x-frag =====
        // A = W1^T (m = n_out), B = x rows (n = row). C: row=m=rg+r, col=n=cl.
        f32x4 acc[6][2];
        #pragma unroll
        for (int mt = 0; mt < 6; ++mt) {
            float4 bv = reinterpret_cast<const float4*>(b1)[mt * 4 + g];
            f32x4 b4 = {bv.x, bv.y, bv.z, bv.w};
            acc[mt][0] = b4; acc[mt][1] = b4;
        }
        bf16x8 xf[2][3];
        #pragma unroll
        for (int nt = 0; nt < 2; ++nt)
            #pragma unroll
            for (int kb = 0; kb < 3; ++kb)
                xf[nt][kb] = *reinterpret_cast<const bf16x8*>(
                    xs + (w*32 + nt*16 + cl) * LDX + kb*32 + g*8);
        #pragma unroll
        for (int mt = 0; mt < 6; ++mt) {
            bf16x8 wfr[3];
            #pragma unroll
            for (int kb = 0; kb < 3; ++kb)
                wfr[kb] = *reinterpret_cast<const bf16x8*>(
                    w1t + (mt*16 + cl) * LDX + kb*32 + g*8);
            #pragma unroll
            for (int nt = 0; nt < 2; ++nt)
                #pragma unroll
                for (int kb = 0; kb < 3; ++kb)
                    acc[mt][nt] = __builtin_amdgcn_mfma_f32_16x16x32_bf16(
                        wfr[kb], xf[nt][kb], acc[mt][nt], 0, 0, 0);
        }

        // epilogue 1: relu -> bf16, b64 write (4 consecutive n_out per lane)
        #pragma unroll
        for (int mt = 0; mt < 6; ++mt)
            #pragma unroll
            for (int nt = 0; nt < 2; ++nt) {
                union { ushort us[4]; uint2 u2; } h4;
                #pragma unroll
                for (int r = 0; r < 4; ++r)
                    h4.us[r] = f2bf(fmaxf(acc[mt][nt][r], 0.f));
                *reinterpret_cast<uint2*>(
                    xs + (w*32 + nt*16 + cl) * LDX + mt*16 + rg) = h4.u2;
            }

        // ===== layer 2 =====
        f32x4 acc2[6][2];
        #pragma unroll
        for (int mt = 0; mt < 6; ++mt) {
            float4 bv = reinterpret_cast<const float4*>(b2)[mt * 4 + g];
            f32x4 b4 = {bv.x, bv.y, bv.z, bv.w};
            acc2[mt][0] = b4; acc2[mt][1] = b4;
        }
        bf16x8 hf[2][3];
        #pragma unroll
        for (int nt = 0; nt < 2; ++nt)
            #pragma unroll
            for (int kb = 0; kb < 3; ++kb)
                hf[nt][kb] = *reinterpret_cast<const bf16x8*>(
                    xs + (w*32 + nt*16 + cl) * LDX + kb*32 + g*8);
        #pragma unroll
        for (int mt = 0; mt < 6; ++mt) {
            bf16x8 wfr[3];
            #pragma unroll
            for (int kb = 0; kb < 3; ++kb)
                wfr[kb] = *reinterpret_cast<const bf16x8*>(
                    w2t + (mt*16 + cl) * LDX + kb*32 + g*8);
            #pragma unroll
            for (int nt = 0; nt < 2; ++nt)
                #pragma unroll
                for (int kb = 0; kb < 3; ++kb)
                    acc2[mt][nt] = __builtin_amdgcn_mfma_f32_16x16x32_bf16(
                        wfr[kb], hf[nt][kb], acc2[mt][nt], 0, 0, 0);
        }

        // epilogue 2: relu + W3 dot in-lane, 2 shuffles, coalesced store
        float pr0 = 0.f, pr1 = 0.f;
        #pragma unroll
        for (int mt = 0; mt < 6; ++mt) {
            float4 w3v = reinterpret_cast<const float4*>(W3)[mt * 4 + g];
            #pragma unroll
            for (int r = 0; r < 4; ++r) {
                float wr = (r == 0) ? w3v.x : (r == 1) ? w3v.y : (r == 2) ? w3v.z : w3v.w;
                pr0 = fmaf(fmaxf(acc2[mt][0][r], 0.f), wr, pr0);
                pr1 = fmaf(fmaxf(acc2[mt][1][r], 0.f), wr, pr1);
            }
        }
        pr0 += __shfl_xor(pr0, 16, 64);
        pr0 += __shfl_xor(pr0, 32, 64);
        pr1 += __shfl_xor(pr1, 16, 64);
        pr1 += __shfl_xor(pr1, 32, 64);
        if (l < 16)
            out[pbase + l] = 0.5f * (pr0 + pr1) + b3[0];
    }
}

extern "C" void kernel_launch(void* const* d_in, const int* in_sizes, int n_in,
                              void* d_out, int out_size, void* d_ws, size_t ws_size,
                              hipStream_t stream) {
    const int*   o1    = (const int*)d_in[0];
    const int*   o2    = (const int*)d_in[1];
    const float* T     = (const float*)d_in[2];
    const float* geoms = (const float*)d_in[3];
    const float* W1    = (const float*)d_in[4];
    const float* b1    = (const float*)d_in[5];
    const float* W2    = (const float*)d_in[6];
    const float* b2    = (const float*)d_in[7];
    const float* W3    = (const float*)d_in[8];
    const float* b3    = (const float*)d_in[9];
    float* out = (float*)d_out;
    const int N  = in_sizes[0];
    const int NG = in_sizes[3];           // 48000

    ushort* gbf = (ushort*)d_ws;
    hipLaunchKernelGGL(prep_geoms, dim3((NG + 255) / 256), dim3(256), 0, stream,
                       geoms, gbf, NG);
    hipLaunchKernelGGL(collision_mfma, dim3(NBLK), dim3(BT), 0, stream,
                       o1, o2, T, geoms, gbf, W1, b1, W2, b2, W3, b3, out, N);
}

// Round 5
// 169.776 us; speedup vs baseline: 2.1746x; 2.1746x over previous
//
#include <hip/hip_runtime.h>

typedef __attribute__((ext_vector_type(8))) short bf16x8;
typedef __attribute__((ext_vector_type(4))) float f32x4;

constexpr int BT   = 256;   // threads/block (4 waves)
constexpr int TP   = 64;    // pairs per tile (16 per wave)
constexpr int KD   = 96;    // feature/hidden dim
constexpr int LDX  = 104;   // row stride in bf16 (208 B: 16B-aligned, odd 32-bank phase)
constexpr int NBLK = 512;   // persistent blocks (2 per CU)

__device__ inline ushort f2bf(float f) {  // fp32 -> bf16 RNE
    uint u = __float_as_uint(f);
    u += 0x7fffu + ((u >> 16) & 1u);
    return (ushort)(u >> 16);
}

// prep: geoms f32 -> bf16 table in d_ws
__global__ void prep_geoms(const float* __restrict__ g, ushort* __restrict__ gb, int n) {
    int i = blockIdx.x * 256 + threadIdx.x;
    if (i < n) gb[i] = f2bf(g[i]);
}

__global__ void __launch_bounds__(BT, 2) collision_mfma(
    const int* __restrict__ o1, const int* __restrict__ o2,
    const float* __restrict__ Tg, const float* __restrict__ geoms,
    const ushort* __restrict__ gbf,
    const float* __restrict__ W1, const float* __restrict__ b1,
    const float* __restrict__ W2, const float* __restrict__ b2,
    const float* __restrict__ W3, const float* __restrict__ b3,
    float* __restrict__ out, int N)
{
    __shared__ ushort xs[128 * LDX];    // x/h tile bf16, wave-private 32-row bands
    __shared__ ushort w1t[KD * LDX];    // W1^T bf16 [n][k]
    __shared__ ushort w2t[KD * LDX];    // W2^T bf16 [n][k]
    __shared__ float  tinv[64 * 16];    // per-pair inverse rows 0..2, stride 16 floats

    const int tid = threadIdx.x;
    const int w   = tid >> 6;      // wave 0..3
    const int l   = tid & 63;      // lane
    const int cl  = l & 15;        // fragment col within 16-tile
    const int g   = l >> 4;        // k-group 0..3
    const int rg  = g * 4;

    // ---- stage weights once: wt[n][k] = W[k][n], bf16 ----
    for (int i = tid; i < KD * KD; i += BT) {
        int k = i / KD;
        int n = i - k * KD;
        w1t[n * LDX + k] = f2bf(W1[i]);
        w2t[n * LDX + k] = f2bf(W2[i]);
    }
    __syncthreads();

    const int ntiles = N / TP;

    for (int tile = blockIdx.x; tile < ntiles; tile += NBLK) {
        const int pbase = tile * TP + w * 16;

        // ===== phase 1: f64 4x4 inverse, lanes 0..15, one pair each =====
        if (l < 16) {
            const int p = pbase + l;
            const float4* T4 = reinterpret_cast<const float4*>(Tg + (size_t)p * 16);
            float4 t0 = T4[0], t1 = T4[1], t2 = T4[2], t3 = T4[3];
            double m00=t0.x, m01=t0.y, m02=t0.z, m03=t0.w;
            double m10=t1.x, m11=t1.y, m12=t1.z, m13=t1.w;
            double m20=t2.x, m21=t2.y, m22=t2.z, m23=t2.w;
            double m30=t3.x, m31=t3.y, m32=t3.z, m33=t3.w;
            double A2323 = m22*m33 - m23*m32;
            double A1323 = m21*m33 - m23*m31;
            double A1223 = m21*m32 - m22*m31;
            double A0323 = m20*m33 - m23*m30;
            double A0223 = m20*m32 - m22*m30;
            double A0123 = m20*m31 - m21*m30;
            double A2313 = m12*m33 - m13*m32;
            double A1313 = m11*m33 - m13*m31;
            double A1213 = m11*m32 - m12*m31;
            double A2312 = m12*m23 - m13*m22;
            double A1312 = m11*m23 - m13*m21;
            double A1212 = m11*m22 - m12*m21;
            double A0313 = m10*m33 - m13*m30;
            double A0213 = m10*m32 - m12*m30;
            double A0312 = m10*m23 - m13*m20;
            double A0212 = m10*m22 - m12*m20;
            double A0113 = m10*m31 - m11*m30;
            double A0112 = m10*m21 - m11*m20;
            double det = m00*(m11*A2323 - m12*A1323 + m13*A1223)
                       - m01*(m10*A2323 - m12*A0323 + m13*A0223)
                       + m02*(m10*A1323 - m11*A0323 + m13*A0123)
                       - m03*(m10*A1223 - m11*A0223 + m12*A0123);
            double idet = 1.0 / det;
            float* ti = &tinv[(w * 16 + l) * 16];
            ti[0]  = (float)( idet *  (m11*A2323 - m12*A1323 + m13*A1223) );
            ti[1]  = (float)( idet * -(m01*A2323 - m02*A1323 + m03*A1223) );
            ti[2]  = (float)( idet *  (m01*A2313 - m02*A1313 + m03*A1213) );
            ti[3]  = (float)( idet * -(m01*A2312 - m02*A1312 + m03*A1212) );
            ti[4]  = (float)( idet * -(m10*A2323 - m12*A0323 + m13*A0223) );
            ti[5]  = (float)( idet *  (m00*A2323 - m02*A0323 + m03*A0223) );
            ti[6]  = (float)( idet * -(m00*A2313 - m02*A0313 + m03*A0213) );
            ti[7]  = (float)( idet *  (m00*A2312 - m02*A0312 + m03*A0212) );
            ti[8]  = (float)( idet *  (m10*A1323 - m11*A0323 + m13*A0123) );
            ti[9]  = (float)( idet * -(m00*A1323 - m01*A0323 + m03*A0123) );
            ti[10] = (float)( idet *  (m00*A1313 - m01*A0313 + m03*A0113) );
            ti[11] = (float)( idet * -(m00*A1312 - m01*A0312 + m03*A0112) );
        }
        __syncthreads();

        // ===== phase 2: staging, lane = half-row =====
        {
            const int rl = l & 31;          // local row 0..31
            const int pt = l >> 5;          // part: elems [pt*24, pt*24+24)
            const int br = rl >> 4;         // branch 0: (x1, T x2)  1: (x2, Tinv x1)
            const int dp = rl & 15;         // local pair
            const int p  = pbase + dp;
            const int ia = o1[p], ib = o2[p];
            const int oa = br ? ib : ia;
            const int ob = br ? ia : ib;
            ushort* xrow = xs + (w * 32 + rl) * LDX;

            // copy half (24 bf16 from pre-converted table)
            {
                const uint4* src = reinterpret_cast<const uint4*>(gbf + oa * 48 + pt * 24);
                uint4* dst = reinterpret_cast<uint4*>(xrow + pt * 24);
                dst[0] = src[0]; dst[1] = src[1]; dst[2] = src[2];
            }

            // transform half: 8 vec3s
            float4 M0, M1, M2;
            if (br == 0) {
                const float4* Tp = reinterpret_cast<const float4*>(Tg + (size_t)p * 16);
                M0 = Tp[0]; M1 = Tp[1]; M2 = Tp[2];
            } else {
                const float4* ti = reinterpret_cast<const float4*>(&tinv[(w * 16 + dp) * 16]);
                M0 = ti[0]; M1 = ti[1]; M2 = ti[2];
            }
            float v[24];
            {
                const float4* bs = reinterpret_cast<const float4*>(geoms + (size_t)ob * 48 + pt * 24);
                #pragma unroll
                for (int q = 0; q < 6; ++q) {
                    float4 t = bs[q];
                    v[4*q+0] = t.x; v[4*q+1] = t.y; v[4*q+2] = t.z; v[4*q+3] = t.w;
                }
            }
            union { ushort us[24]; uint4 q4[3]; } pk;
            #pragma unroll
            for (int m = 0; m < 8; ++m) {
                float vx = v[3*m+0], vy = v[3*m+1], vz = v[3*m+2];
                pk.us[3*m+0] = f2bf(fmaf(M0.x, vx, fmaf(M0.y, vy, fmaf(M0.z, vz, M0.w))));
                pk.us[3*m+1] = f2bf(fmaf(M1.x, vx, fmaf(M1.y, vy, fmaf(M1.z, vz, M1.w))));
                pk.us[3*m+2] = f2bf(fmaf(M2.x, vx, fmaf(M2.y, vy, fmaf(M2.z, vz, M2.w))));
            }
            uint4* dst = reinterpret_cast<uint4*>(xrow + 48 + pt * 24);
            dst[0] = pk.q4[0]; dst[1] = pk.q4[1]; dst[2] = pk.q4[2];
        }
        __syncthreads();

        // ===== layer 1: acc[mt][nt] = W1^T-frag x x-frag (zero-init, bias in epilogue) =====
        f32x4 acc[6][2];
        #pragma unroll
        for (int mt = 0; mt < 6; ++mt) {
            acc[mt][0] = (f32x4){0.f, 0.f, 0.f, 0.f};
            acc[mt][1] = (f32x4){0.f, 0.f, 0.f, 0.f};
        }
        bf16x8 xf[2][3];
        #pragma unroll
        for (int nt = 0; nt < 2; ++nt)
            #pragma unroll
            for (int kb = 0; kb < 3; ++kb)
                xf[nt][kb] = *reinterpret_cast<const bf16x8*>(
                    xs + (w*32 + nt*16 + cl) * LDX + kb*32 + g*8);
        #pragma unroll
        for (int mt = 0; mt < 6; ++mt) {
            bf16x8 wfr[3];
            #pragma unroll
            for (int kb = 0; kb < 3; ++kb)
                wfr[kb] = *reinterpret_cast<const bf16x8*>(
                    w1t + (mt*16 + cl) * LDX + kb*32 + g*8);
            #pragma unroll
            for (int nt = 0; nt < 2; ++nt)
                #pragma unroll
                for (int kb = 0; kb < 3; ++kb)
                    acc[mt][nt] = __builtin_amdgcn_mfma_f32_16x16x32_bf16(
                        wfr[kb], xf[nt][kb], acc[mt][nt], 0, 0, 0);
        }

        // epilogue 1: +bias, relu -> bf16, b64 write (4 consecutive n_out per lane)
        #pragma unroll
        for (int mt = 0; mt < 6; ++mt) {
            float4 bv = *reinterpret_cast<const float4*>(b1 + mt*16 + rg);
            #pragma unroll
            for (int nt = 0; nt < 2; ++nt) {
                union { ushort us[4]; uint2 u2; } h4;
                h4.us[0] = f2bf(fmaxf(acc[mt][nt][0] + bv.x, 0.f));
                h4.us[1] = f2bf(fmaxf(acc[mt][nt][1] + bv.y, 0.f));
                h4.us[2] = f2bf(fmaxf(acc[mt][nt][2] + bv.z, 0.f));
                h4.us[3] = f2bf(fmaxf(acc[mt][nt][3] + bv.w, 0.f));
                *reinterpret_cast<uint2*>(
                    xs + (w*32 + nt*16 + cl) * LDX + mt*16 + rg) = h4.u2;
            }
        }

        // ===== layer 2 ===== (h-tile rows are wave-private; no barrier needed)
        f32x4 acc2[6][2];
        #pragma unroll
        for (int mt = 0; mt < 6; ++mt) {
            acc2[mt][0] = (f32x4){0.f, 0.f, 0.f, 0.f};
            acc2[mt][1] = (f32x4){0.f, 0.f, 0.f, 0.f};
        }
        bf16x8 hf[2][3];
        #pragma unroll
        for (int nt = 0; nt < 2; ++nt)
            #pragma unroll
            for (int kb = 0; kb < 3; ++kb)
                hf[nt][kb] = *reinterpret_cast<const bf16x8*>(
                    xs + (w*32 + nt*16 + cl) * LDX + kb*32 + g*8);
        #pragma unroll
        for (int mt = 0; mt < 6; ++mt) {
            bf16x8 wfr[3];
            #pragma unroll
            for (int kb = 0; kb < 3; ++kb)
                wfr[kb] = *reinterpret_cast<const bf16x8*>(
                    w2t + (mt*16 + cl) * LDX + kb*32 + g*8);
            #pragma unroll
            for (int nt = 0; nt < 2; ++nt)
                #pragma unroll
                for (int kb = 0; kb < 3; ++kb)
                    acc2[mt][nt] = __builtin_amdgcn_mfma_f32_16x16x32_bf16(
                        wfr[kb], hf[nt][kb], acc2[mt][nt], 0, 0, 0);
        }

        // epilogue 2: +bias, relu, W3 dot in-lane, 2 shuffles, coalesced store
        float pr0 = 0.f, pr1 = 0.f;
        #pragma unroll
        for (int mt = 0; mt < 6; ++mt) {
            float4 bv  = *reinterpret_cast<const float4*>(b2 + mt*16 + rg);
            float4 w3v = *reinterpret_cast<const float4*>(W3 + mt*16 + rg);
            pr0 = fmaf(fmaxf(acc2[mt][0][0] + bv.x, 0.f), w3v.x, pr0);
            pr0 = fmaf(fmaxf(acc2[mt][0][1] + bv.y, 0.f), w3v.y, pr0);
            pr0 = fmaf(fmaxf(acc2[mt][0][2] + bv.z, 0.f), w3v.z, pr0);
            pr0 = fmaf(fmaxf(acc2[mt][0][3] + bv.w, 0.f), w3v.w, pr0);
            pr1 = fmaf(fmaxf(acc2[mt][1][0] + bv.x, 0.f), w3v.x, pr1);
            pr1 = fmaf(fmaxf(acc2[mt][1][1] + bv.y, 0.f), w3v.y, pr1);
            pr1 = fmaf(fmaxf(acc2[mt][1][2] + bv.z, 0.f), w3v.z, pr1);
            pr1 = fmaf(fmaxf(acc2[mt][1][3] + bv.w, 0.f), w3v.w, pr1);
        }
        pr0 += __shfl_xor(pr0, 16, 64);
        pr0 += __shfl_xor(pr0, 32, 64);
        pr1 += __shfl_xor(pr1, 16, 64);
        pr1 += __shfl_xor(pr1, 32, 64);
        if (l < 16)
            out[pbase + l] = 0.5f * (pr0 + pr1) + b3[0];
    }
}

extern "C" void kernel_launch(void* const* d_in, const int* in_sizes, int n_in,
                              void* d_out, int out_size, void* d_ws, size_t ws_size,
                              hipStream_t stream) {
    const int*   o1    = (const int*)d_in[0];
    const int*   o2    = (const int*)d_in[1];
    const float* T     = (const float*)d_in[2];
    const float* geoms = (const float*)d_in[3];
    const float* W1    = (const float*)d_in[4];
    const float* b1    = (const float*)d_in[5];
    const float* W2    = (const float*)d_in[6];
    const float* b2    = (const float*)d_in[7];
    const float* W3    = (const float*)d_in[8];
    const float* b3    = (const float*)d_in[9];
    float* out = (float*)d_out;
    const int N  = in_sizes[0];
    const int NG = in_sizes[3];           // 48000

    ushort* gbf = (ushort*)d_ws;
    hipLaunchKernelGGL(prep_geoms, dim3((NG + 255) / 256), dim3(256), 0, stream,
                       geoms, gbf, NG);
    hipLaunchKernelGGL(collision_mfma, dim3(NBLK), dim3(BT), 0, stream,
                       o1, o2, T, geoms, gbf, W1, b1, W2, b2, W3, b3, out, N);
}